// Round 4
// baseline (126.748 us; speedup 1.0000x reference)
//
#include <hip/hip_runtime.h>

// B=16, T=2048, C=200, H=64 attention head with padding mask.
// Round 10: (a) qkv_proj was 2 waves/SIMD grid-limited (~30us vs ~7us roofline) -> split H
// across 2x blocks: grid 1024, 38.4KB LDS, 24 AGPR acc -> 4 blocks/CU = 4 waves/SIMD.
// x read twice (+26MB, L3-absorbed). (b) attn: s_setprio(1) around MFMA clusters (T5;
// attn waves are barrier-free/phase-diverse -> the regime where it measured +4-7%).
// attn structure otherwise round-9 (44.8us plateau, reg-capped at 2 waves/SIMD).

typedef __attribute__((ext_vector_type(8))) __bf16 bf16x8;
typedef __attribute__((ext_vector_type(4))) __bf16 bf16x4;
typedef __attribute__((ext_vector_type(4))) float f32x4;

#define T_SEQ 2048
#define C_DIM 200
#define H_DIM 64
#define BT_TOT 32768
#define QKV_ELEMS 2097152
#define PPAD 72            // P row pad (bf16): 2-way bank alias only
#define OPAD 68            // combine row pad (f32)
#define WTF_FULL 36864     // ks 0..5 full chunks: 6 * (3w*4t) * 512
#define WTF_ELEMS 38400    // + compact ks=6 chunk: 3*4*128 (c=192..199 only)
#define LOG2E 1.44269504088896f

// ---------------- Kernel 0: repack weights, compact MFMA fragment order ----------------
// Full chunk (ks<6, w, t): 512 bf16, elem lane*8+j = W_w[c=ks*32+(lane>>4)*8+j][h=t*16+(lane&15)]
// Compact ks=6 chunk (w, t): 128 bf16, elem l15*8+j = W_w[c=192+j][h=t*16+l15].
// w0 = Wq * (H^-0.5 * log2 e): scores land in log2 domain.
__global__ void prep_w(const float* __restrict__ Wk, const float* __restrict__ Wq,
                       const float* __restrict__ Wv, __bf16* __restrict__ WtF) {
    int idx = blockIdx.x * 256 + threadIdx.x;
    if (idx >= WTF_ELEMS) return;
    int w, c, h;
    if (idx < WTF_FULL) {
        int j = idx & 7, lane = (idx >> 3) & 63;
        int chunk = idx >> 9;                 // ks*12 + w*4 + t
        int t = chunk & 3, rest = chunk >> 2; // ks*3 + w
        w = rest % 3; int ks = rest / 3;
        c = ks * 32 + (lane >> 4) * 8 + j;
        h = t * 16 + (lane & 15);
    } else {
        int i2 = idx - WTF_FULL;
        int j = i2 & 7, l15 = (i2 >> 3) & 15, t = (i2 >> 7) & 3;
        w = i2 >> 9;
        c = 192 + j;
        h = t * 16 + l15;
    }
    const float* W = (w == 0) ? Wq : (w == 1) ? Wk : Wv;  // [C][H]
    float val = W[c * H_DIM + h];
    if (w == 0) val *= 0.125f * LOG2E;
    WtF[idx] = (__bf16)val;
}

// ---------------- Kernel 1: QKV projection, H-split ----------------
// grid = 1024 blocks (512 row-tiles x 2 h-halves) x 256 threads (4 waves x 16 rows).
// Each block: 64 rows, 32 of 64 output cols. 38.4KB LDS -> 4 blocks/CU = 4 waves/SIMD.
__global__ __launch_bounds__(256) void qkv_proj(const float* __restrict__ x,
                                                const __bf16* __restrict__ WtF,
                                                __bf16* __restrict__ qb,
                                                __bf16* __restrict__ kb,
                                                __bf16* __restrict__ vT) {
    __shared__ __bf16 Wl[19200];  // 38400 B; reused for transpose epilogue

    const int tid = threadIdx.x;
    const int wave = tid >> 6, lane = tid & 63, l15 = lane & 15, quad = lane >> 4;
    const int rt = blockIdx.x >> 1;        // row tile
    const int hh = blockIdx.x & 1;         // h half: cols [hh*32, hh*32+32)
    const int m0b = rt * 64;
    const int row0 = m0b + wave * 16;

    f32x4 acc[3][2] = {};  // [w][local h-tile], 16 rows per wave

    // ---- stage this half's W chunks: 2400 x 16B units over 256 threads = 10 guarded iters ----
    #pragma unroll
    for (int i = 0; i < 10; ++i) {
        const int u = i * 256 + tid;
        if (u < 2400) {
            int src;
            if (u < 2304) {
                const int lc = u >> 6, off = u & 63;        // local full chunk, unit within
                const int ks = lc / 6, r6 = lc % 6;
                const int w = r6 >> 1, tt = r6 & 1;
                src = ((ks * 12 + w * 4 + 2 * hh + tt) << 6) + off;
            } else {
                const int u2 = u - 2304;                     // compact ks=6 region
                const int w = u2 >> 5, tt = (u2 >> 4) & 1, un = u2 & 15;
                src = (WTF_FULL >> 3) + ((w * 4 + 2 * hh + tt) << 4) + un;
            }
            *(bf16x8*)(Wl + u * 8) = *(const bf16x8*)(WtF + src * 8);
        }
    }
    __syncthreads();

    // ---- compute: 7 ks steps, 3 w, 2 local h-tiles ----
    #pragma unroll
    for (int ks = 0; ks < 7; ++ks) {
        bf16x8 a;
        if (ks < 6 || quad == 0) {
            // ks=6,quad0 reads c 192..199 exactly (in-bounds); other quads are c>=200 -> A=0
            const float* xr = x + (size_t)(row0 + l15) * C_DIM + ks * 32 + quad * 8;
            const float4 f0 = *(const float4*)xr;
            const float4 f1 = *(const float4*)(xr + 4);
            a[0]=(__bf16)f0.x; a[1]=(__bf16)f0.y; a[2]=(__bf16)f0.z; a[3]=(__bf16)f0.w;
            a[4]=(__bf16)f1.x; a[5]=(__bf16)f1.y; a[6]=(__bf16)f1.z; a[7]=(__bf16)f1.w;
        } else {
            #pragma unroll
            for (int j = 0; j < 8; ++j) a[j] = (__bf16)0.f;
        }
        #pragma unroll
        for (int w = 0; w < 3; ++w)
            #pragma unroll
            for (int tt = 0; tt < 2; ++tt) {
                // ks=6: compact chunk; quads 1..3 read quad0's data -> harmless (A rows are 0)
                const int off = (ks < 6) ? (((ks * 6 + w * 2 + tt) << 9) + lane * 8)
                                         : (18432 + ((w * 2 + tt) << 7) + l15 * 8);
                const bf16x8 bf = *(const bf16x8*)(Wl + off);
                acc[w][tt] = __builtin_amdgcn_mfma_f32_16x16x32_bf16(a, bf, acc[w][tt], 0, 0, 0);
            }
    }

    // ---- epilogue: q,k direct stores; vT via LDS transpose for coalesced b128 ----
    #pragma unroll
    for (int tt = 0; tt < 2; ++tt)
        #pragma unroll
        for (int r = 0; r < 4; ++r) {
            const size_t m = row0 + quad * 4 + r;
            const int h = hh * 32 + tt * 16 + l15;
            qb[m * H_DIM + h] = (__bf16)acc[0][tt][r];
            kb[m * H_DIM + h] = (__bf16)acc[1][tt][r];
        }
    __syncthreads();
    #pragma unroll
    for (int tt = 0; tt < 2; ++tt)
        #pragma unroll
        for (int r = 0; r < 4; ++r)
            Wl[(tt * 16 + l15) * 72 + wave * 16 + quad * 4 + r] = (__bf16)acc[2][tt][r];
    __syncthreads();
    const int bb = m0b >> 11, tloc = m0b & 2047;
    {
        const int seg = tid;                    // 256 segs: local h row (32), 8-elem col chunk (8)
        const int hl = seg >> 3, s8 = seg & 7;
        *(bf16x8*)(vT + ((size_t)bb * H_DIM + hh * 32 + hl) * T_SEQ + tloc + s8 * 8) =
            *(const bf16x8*)(Wl + hl * 72 + s8 * 8);
    }
}

// ---------------- Kernel 2: attention, 64 queries/wave, pipelined K-loop + setprio ----------------
// grid = (T/64, B); block = 256 (4 waves = 4 key-splits of 512, all same 64-q tile).
// No-max softmax in log2 domain (S~N(0,1): exp safe in fp32; masked keys -> exact 0).
__global__ __launch_bounds__(256, 2) void attn(const __bf16* __restrict__ qb,
                                               const __bf16* __restrict__ kb,
                                               const __bf16* __restrict__ vT,
                                               const int* __restrict__ pm,
                                               float* __restrict__ out) {
    // arena: [0,8K) key bias f32[2048]; [8K,+36864) per-wave P (4 x 64 x PPAD bf16),
    // unioned with combine region Ocomb[64][OPAD] f32 + Lcomb[64] f32.
    __shared__ __align__(16) char arena[8192 + 36864];
    float* biasS = (float*)arena;

    const int tid = threadIdx.x;
    const int wave = tid >> 6, lane = tid & 63, l15 = lane & 15, quad = lane >> 4;
    const int ks = wave;
    const int b = blockIdx.y;
    const int q0 = blockIdx.x * 64;
    const size_t bT = (size_t)b * T_SEQ;

    for (int i = tid; i < 512; i += 256) {
        const int4 p4 = *(const int4*)(pm + bT + i * 4);
        biasS[i * 4 + 0] = p4.x ? 0.f : -1e30f;
        biasS[i * 4 + 1] = p4.y ? 0.f : -1e30f;
        biasS[i * 4 + 2] = p4.z ? 0.f : -1e30f;
        biasS[i * 4 + 3] = p4.w ? 0.f : -1e30f;
    }
    __syncthreads();

    // Q fragments: qa[mt][s], lane holds Q[q0+mt*16+l15][s*32+quad*8 ..+8]
    bf16x8 qa[4][2];
    #pragma unroll
    for (int mt = 0; mt < 4; ++mt)
        #pragma unroll
        for (int s = 0; s < 2; ++s)
            qa[mt][s] = *(const bf16x8*)(qb + (bT + q0 + mt * 16 + l15) * H_DIM + s * 32 + quad * 8);

    __bf16* P = (__bf16*)(arena + 8192) + wave * (64 * PPAD);
    const __bf16* kbase = kb + bT * H_DIM;
    const __bf16* vbase = vT + (size_t)b * H_DIM * T_SEQ;

    f32x4 oacc[4][4] = {};              // O'[qtile][h-tile][row=quad*4+r]
    float lsum[4] = {0.f, 0.f, 0.f, 0.f};

    // preload K and V fragments for tile 0
    bf16x8 kf[8];   // kf[n*2+s] = K[key0+n*16+l15][s*32+quad*8 ..+8]
    bf16x8 vf[8];   // vf[t*2+s] = V^T[t*16+l15][key0+s*32+quad*8 ..+8]
    #pragma unroll
    for (int n = 0; n < 4; ++n)
        #pragma unroll
        for (int s = 0; s < 2; ++s)
            kf[n * 2 + s] = *(const bf16x8*)(kbase + (ks * 512 + n * 16 + l15) * H_DIM + s * 32 + quad * 8);
    #pragma unroll
    for (int t = 0; t < 4; ++t)
        #pragma unroll
        for (int s = 0; s < 2; ++s)
            vf[t * 2 + s] = *(const bf16x8*)(vbase + (size_t)(t * 16 + l15) * T_SEQ + ks * 512 + s * 32 + quad * 8);

    for (int kt = 0; kt < 8; ++kt) {
        const int key0 = ks * 512 + kt * 64;
        const int keyn = ks * 512 + ((kt < 7) ? kt + 1 : 7) * 64;  // clamped prefetch addr

        bf16x8 pa[4][2];

        // ---- QK half 1: n-blocks 0,1 -> exp -> P rows; then issue pa[s=0] reads ----
        #pragma unroll
        for (int n = 0; n < 2; ++n) {
            const f32x4 bias = *(const f32x4*)(biasS + key0 + n * 16 + quad * 4);
            f32x4 s_[4];
            #pragma unroll
            for (int mt = 0; mt < 4; ++mt) s_[mt] = bias;
            __builtin_amdgcn_s_setprio(1);
            #pragma unroll
            for (int s = 0; s < 2; ++s)
                #pragma unroll
                for (int mt = 0; mt < 4; ++mt)
                    s_[mt] = __builtin_amdgcn_mfma_f32_16x16x32_bf16(kf[n * 2 + s], qa[mt][s], s_[mt], 0, 0, 0);
            __builtin_amdgcn_s_setprio(0);
            #pragma unroll
            for (int mt = 0; mt < 4; ++mt) {
                bf16x4 p4;
                #pragma unroll
                for (int r = 0; r < 4; ++r) {
                    const float e = exp2f(s_[mt][r]);
                    lsum[mt] += e;
                    p4[r] = (__bf16)e;
                }
                *(bf16x4*)(P + (mt * 16 + l15) * PPAD + n * 16 + quad * 4) = p4;
            }
        }
        // pa[s=0] covers keys 0..31 = n-blocks 0,1 only; DS in-order within wave means
        // these reads wait only on the writes above, and their latency hides under QK n=2,3.
        #pragma unroll
        for (int mt = 0; mt < 4; ++mt)
            pa[mt][0] = *(const bf16x8*)(P + (mt * 16 + l15) * PPAD + quad * 8);

        // ---- QK half 2: n-blocks 2,3 -> exp -> P rows; then issue pa[s=1] reads ----
        #pragma unroll
        for (int n = 2; n < 4; ++n) {
            const f32x4 bias = *(const f32x4*)(biasS + key0 + n * 16 + quad * 4);
            f32x4 s_[4];
            #pragma unroll
            for (int mt = 0; mt < 4; ++mt) s_[mt] = bias;
            __builtin_amdgcn_s_setprio(1);
            #pragma unroll
            for (int s = 0; s < 2; ++s)
                #pragma unroll
                for (int mt = 0; mt < 4; ++mt)
                    s_[mt] = __builtin_amdgcn_mfma_f32_16x16x32_bf16(kf[n * 2 + s], qa[mt][s], s_[mt], 0, 0, 0);
            __builtin_amdgcn_s_setprio(0);
            #pragma unroll
            for (int mt = 0; mt < 4; ++mt) {
                bf16x4 p4;
                #pragma unroll
                for (int r = 0; r < 4; ++r) {
                    const float e = exp2f(s_[mt][r]);
                    lsum[mt] += e;
                    p4[r] = (__bf16)e;
                }
                *(bf16x4*)(P + (mt * 16 + l15) * PPAD + n * 16 + quad * 4) = p4;
            }
        }
        #pragma unroll
        for (int mt = 0; mt < 4; ++mt)
            pa[mt][1] = *(const bf16x8*)(P + (mt * 16 + l15) * PPAD + 32 + quad * 8);

        // ---- K prefetch for next tile (kf dead after QK half 2) ----
        #pragma unroll
        for (int n = 0; n < 4; ++n)
            #pragma unroll
            for (int s = 0; s < 2; ++s)
                kf[n * 2 + s] = *(const bf16x8*)(kbase + (keyn + n * 16 + l15) * H_DIM + s * 32 + quad * 8);

        // ---- PV s=0 (pa[s=1] DS latency hides under these 16 MFMAs) ----
        __builtin_amdgcn_s_setprio(1);
        #pragma unroll
        for (int t = 0; t < 4; ++t)
            #pragma unroll
            for (int mt = 0; mt < 4; ++mt)
                oacc[mt][t] = __builtin_amdgcn_mfma_f32_16x16x32_bf16(pa[mt][0], vf[t * 2 + 0], oacc[mt][t], 0, 0, 0);

        // ---- PV s=1 ----
        #pragma unroll
        for (int t = 0; t < 4; ++t)
            #pragma unroll
            for (int mt = 0; mt < 4; ++mt)
                oacc[mt][t] = __builtin_amdgcn_mfma_f32_16x16x32_bf16(pa[mt][1], vf[t * 2 + 1], oacc[mt][t], 0, 0, 0);
        __builtin_amdgcn_s_setprio(0);

        // ---- V prefetch for next tile (vf dead after PV s=1) ----
        if (kt < 7) {
            #pragma unroll
            for (int t = 0; t < 4; ++t)
                #pragma unroll
                for (int s = 0; s < 2; ++s)
                    vf[t * 2 + s] = *(const bf16x8*)(vbase + (size_t)(t * 16 + l15) * T_SEQ + keyn + s * 32 + quad * 8);
        }
    }

    #pragma unroll
    for (int mt = 0; mt < 4; ++mt) {
        lsum[mt] += __shfl_xor(lsum[mt], 16, 64);
        lsum[mt] += __shfl_xor(lsum[mt], 32, 64);
    }

    // in-LDS combine over the 4 key-splits (sequential; one 64-q tile per block)
    float* Ocomb = (float*)(arena + 8192);   // [64][OPAD]
    float* Lcomb = Ocomb + 64 * OPAD;        // [64]

    __syncthreads();
    if (ks == 1) {
        #pragma unroll
        for (int mt = 0; mt < 4; ++mt) {
            #pragma unroll
            for (int t = 0; t < 4; ++t)
                #pragma unroll
                for (int r = 0; r < 4; ++r)
                    Ocomb[(mt * 16 + quad * 4 + r) * OPAD + t * 16 + l15] = oacc[mt][t][r];
            if (quad == 0) Lcomb[mt * 16 + l15] = lsum[mt];
        }
    }
    __syncthreads();
    if (ks == 2) {
        #pragma unroll
        for (int mt = 0; mt < 4; ++mt) {
            #pragma unroll
            for (int t = 0; t < 4; ++t)
                #pragma unroll
                for (int r = 0; r < 4; ++r)
                    Ocomb[(mt * 16 + quad * 4 + r) * OPAD + t * 16 + l15] += oacc[mt][t][r];
            if (quad == 0) Lcomb[mt * 16 + l15] += lsum[mt];
        }
    }
    __syncthreads();
    if (ks == 3) {
        #pragma unroll
        for (int mt = 0; mt < 4; ++mt) {
            #pragma unroll
            for (int t = 0; t < 4; ++t)
                #pragma unroll
                for (int r = 0; r < 4; ++r)
                    Ocomb[(mt * 16 + quad * 4 + r) * OPAD + t * 16 + l15] += oacc[mt][t][r];
            if (quad == 0) Lcomb[mt * 16 + l15] += lsum[mt];
        }
    }
    __syncthreads();
    if (ks == 0) {
        #pragma unroll
        for (int mt = 0; mt < 4; ++mt) {
            lsum[mt] += Lcomb[mt * 16 + l15];
            #pragma unroll
            for (int t = 0; t < 4; ++t)
                #pragma unroll
                for (int r = 0; r < 4; ++r)
                    oacc[mt][t][r] += Ocomb[(mt * 16 + quad * 4 + r) * OPAD + t * 16 + l15];
            #pragma unroll
            for (int r = 0; r < 4; ++r) {
                const int qpos = q0 + mt * 16 + quad * 4 + r;
                const float lv = __shfl(lsum[mt], quad * 4 + r, 64);
                const bool qvalid = biasS[qpos] == 0.f;  // query mask == key mask (pm[b][t])
                const float inv = (qvalid && lv > 0.f) ? 1.f / lv : 0.f;
                #pragma unroll
                for (int t = 0; t < 4; ++t)
                    out[(bT + qpos) * H_DIM + t * 16 + l15] = oacc[mt][t][r] * inv;
            }
        }
    }
}

extern "C" void kernel_launch(void* const* d_in, const int* in_sizes, int n_in,
                              void* d_out, int out_size, void* d_ws, size_t ws_size,
                              hipStream_t stream) {
    const float* x  = (const float*)d_in[0];
    const int* pm   = (const int*)d_in[1];
    const float* Wk = (const float*)d_in[2];
    const float* Wq = (const float*)d_in[3];
    const float* Wv = (const float*)d_in[4];
    float* out = (float*)d_out;

    // ws: qb | kb | vT (bf16, 4MB each) | WtF (76.8KB)
    __bf16* qb  = (__bf16*)d_ws;
    __bf16* kb  = qb + QKV_ELEMS;
    __bf16* vT  = kb + QKV_ELEMS;
    __bf16* WtF = vT + QKV_ELEMS;

    prep_w<<<dim3((WTF_ELEMS + 255) / 256), dim3(256), 0, stream>>>(Wk, Wq, Wv, WtF);
    qkv_proj<<<dim3(BT_TOT / 64 * 2), dim3(256), 0, stream>>>(x, WtF, qb, kb, vT);
    attn<<<dim3(T_SEQ / 64, 16), dim3(256), 0, stream>>>(qb, kb, vT, pm, out);
}